// Round 1
// baseline (10013.945 us; speedup 1.0000x reference)
//
#include <hip/hip_runtime.h>
#include <math.h>

#define BB 8
#define SEQN 1025
#define DD 1024
#define HH 8
#define HD 128
#define LL 2
#define MROWS (BB*SEQN)     // 8200
#define NBUCKET 64

__device__ __forceinline__ float silu_f(float x) { return x / (1.f + expf(-x)); }

// ---------------- copy seqs -> h ----------------
__global__ __launch_bounds__(256) void copy_kernel(const float* __restrict__ in,
                                                   float* __restrict__ out, int n4) {
  int idx = blockIdx.x * blockDim.x + threadIdx.x;
  int stride = gridDim.x * blockDim.x;
  const float4* i4 = (const float4*)in;
  float4* o4 = (float4*)out;
  for (int i = idx; i < n4; i += stride) o4[i] = i4[i];
}

// ---------------- rel-attn bias [B,N,N] ----------------
__global__ __launch_bounds__(256) void bias_kernel(const int* __restrict__ ts,
    const float* __restrict__ ts_w, const float* __restrict__ pos_w,
    float* __restrict__ bias)
{
  int j = blockIdx.x * 256 + threadIdx.x;
  int i = blockIdx.y;
  int b = blockIdx.z;
  if (j >= SEQN) return;
  int ip1 = i + 1; if (ip1 > SEQN - 1) ip1 = SEQN - 1;
  long long t1 = (long long)ts[b * SEQN + ip1];
  long long t0 = (long long)ts[b * SEQN + j];
  long long d = t1 - t0;
  if (d < 0) d = -d;
  if (d < 1) d = 1;
  int bucket = (int)(logf((float)d) / 0.301f);   // trunc toward zero, log >= 0
  if (bucket < 0) bucket = 0;
  if (bucket > NBUCKET) bucket = NBUCKET;
  bias[((size_t)(b * SEQN + i)) * SEQN + j] = pos_w[j - i + SEQN - 1] + ts_w[bucket];
}

// ---------------- row norms ----------------
__global__ __launch_bounds__(256) void ln_kernel(const float* __restrict__ in,
                                                 float* __restrict__ out) {
  int row = blockIdx.x;
  int tid = threadIdx.x;
  const float* x = in + (size_t)row * DD;
  float4 v = *(const float4*)&x[tid * 4];
  float s = v.x + v.y + v.z + v.w;
  float ss = v.x*v.x + v.y*v.y + v.z*v.z + v.w*v.w;
#pragma unroll
  for (int off = 32; off >= 1; off >>= 1) { s += __shfl_xor(s, off); ss += __shfl_xor(ss, off); }
  __shared__ float red0[4], red1[4];
  if ((tid & 63) == 0) { red0[tid >> 6] = s; red1[tid >> 6] = ss; }
  __syncthreads();
  s = red0[0] + red0[1] + red0[2] + red0[3];
  ss = red1[0] + red1[1] + red1[2] + red1[3];
  float mu = s * (1.f / DD);
  float var = fmaxf(ss * (1.f / DD) - mu * mu, 0.f);
  float inv = 1.f / sqrtf(var + 1e-8f);
  float4 o;
  o.x = (v.x - mu) * inv; o.y = (v.y - mu) * inv;
  o.z = (v.z - mu) * inv; o.w = (v.w - mu) * inv;
  *(float4*)&out[(size_t)row * DD + tid * 4] = o;
}

__global__ __launch_bounds__(256) void rms_kernel(const float* __restrict__ in,
                                                  float* __restrict__ out) {
  int row = blockIdx.x;
  int tid = threadIdx.x;
  const float* x = in + (size_t)row * DD;
  float4 v = *(const float4*)&x[tid * 4];
  float ss = v.x*v.x + v.y*v.y + v.z*v.z + v.w*v.w;
#pragma unroll
  for (int off = 32; off >= 1; off >>= 1) ss += __shfl_xor(ss, off);
  __shared__ float red1[4];
  if ((tid & 63) == 0) red1[tid >> 6] = ss;
  __syncthreads();
  ss = red1[0] + red1[1] + red1[2] + red1[3];
  float inv = 1.f / sqrtf(ss * (1.f / DD) + 1e-8f);
  float4 o;
  o.x = v.x * inv; o.y = v.y * inv; o.z = v.z * inv; o.w = v.w * inv;
  *(float4*)&out[(size_t)row * DD + tid * 4] = o;
}

// out[d] = u[d] * layernorm(av)[d]
__global__ __launch_bounds__(256) void uln_kernel(const float* __restrict__ av,
    const float* __restrict__ act, float* __restrict__ out) {
  int row = blockIdx.x;
  int tid = threadIdx.x;
  const float* x = av + (size_t)row * DD;
  float4 v = *(const float4*)&x[tid * 4];
  float s = v.x + v.y + v.z + v.w;
  float ss = v.x*v.x + v.y*v.y + v.z*v.z + v.w*v.w;
#pragma unroll
  for (int off = 32; off >= 1; off >>= 1) { s += __shfl_xor(s, off); ss += __shfl_xor(ss, off); }
  __shared__ float red0[4], red1[4];
  if ((tid & 63) == 0) { red0[tid >> 6] = s; red1[tid >> 6] = ss; }
  __syncthreads();
  s = red0[0] + red0[1] + red0[2] + red0[3];
  ss = red1[0] + red1[1] + red1[2] + red1[3];
  float mu = s * (1.f / DD);
  float var = fmaxf(ss * (1.f / DD) - mu * mu, 0.f);
  float inv = 1.f / sqrtf(var + 1e-8f);
  float4 u = *(const float4*)&act[(size_t)row * 4096 + 3072 + tid * 4];
  float4 o;
  o.x = u.x * (v.x - mu) * inv; o.y = u.y * (v.y - mu) * inv;
  o.z = u.z * (v.z - mu) * inv; o.w = u.w * (v.w - mu) * inv;
  *(float4*)&out[(size_t)row * DD + tid * 4] = o;
}

// ---------------- f32 GEMM: C[M,Nn] (+epilogue) = A[M,K] @ W[K,Nn] ----------------
// MODE 0: C = silu(AW);  MODE 1: C += AW + bvec;  MODE 2: C = AW + bvec
// GATED: A[m,k] = silu(vg[m,2048+k]) * vg[m,k]  (lda = 4096)
template<int MODE, bool GATED>
__global__ __launch_bounds__(256) void gemm_kernel(
    const float* __restrict__ A, const float* __restrict__ W,
    const float* __restrict__ bvec, float* __restrict__ C,
    int M, int Nn, int K, int lda)
{
  __shared__ __align__(16) float As[8][132];
  __shared__ __align__(16) float Bs[8][132];
  int tid = threadIdx.x;
  int tx = tid & 15, ty = tid >> 4;
  int bm = blockIdx.y * 128, bn = blockIdx.x * 128;
  float acc[8][8];
#pragma unroll
  for (int r = 0; r < 8; r++)
#pragma unroll
    for (int c = 0; c < 8; c++) acc[r][c] = 0.f;

  int am = tid >> 1;            // 0..127 (A row in tile)
  int ak = (tid & 1) * 4;       // 0 or 4
  int bk = tid >> 5;            // 0..7  (B row in tile)
  int bc = (tid & 31) * 4;      // 0..124
  bool avalid = (bm + am) < M;
  const float* Arow = A + (size_t)(bm + am) * lda;
  int nk = K >> 3;
  for (int kb = 0; kb < nk; kb++) {
    int k0 = kb << 3;
    float4 a4 = {0.f, 0.f, 0.f, 0.f};
    if (avalid) {
      if (GATED) {
        float4 vv = *(const float4*)&Arow[k0 + ak];
        float4 gg = *(const float4*)&Arow[2048 + k0 + ak];
        a4.x = silu_f(gg.x) * vv.x; a4.y = silu_f(gg.y) * vv.y;
        a4.z = silu_f(gg.z) * vv.z; a4.w = silu_f(gg.w) * vv.w;
      } else {
        a4 = *(const float4*)&Arow[k0 + ak];
      }
    }
    float4 b4 = *(const float4*)&W[(size_t)(k0 + bk) * Nn + bn + bc];
    As[ak + 0][am] = a4.x; As[ak + 1][am] = a4.y;
    As[ak + 2][am] = a4.z; As[ak + 3][am] = a4.w;
    *(float4*)&Bs[bk][bc] = b4;
    __syncthreads();
#pragma unroll
    for (int kk = 0; kk < 8; kk++) {
      float4 a0 = *(const float4*)&As[kk][ty * 4];
      float4 a1 = *(const float4*)&As[kk][64 + ty * 4];
      float4 b0 = *(const float4*)&Bs[kk][tx * 4];
      float4 b1 = *(const float4*)&Bs[kk][64 + tx * 4];
      float ar[8] = {a0.x, a0.y, a0.z, a0.w, a1.x, a1.y, a1.z, a1.w};
      float br[8] = {b0.x, b0.y, b0.z, b0.w, b1.x, b1.y, b1.z, b1.w};
#pragma unroll
      for (int r = 0; r < 8; r++)
#pragma unroll
        for (int c = 0; c < 8; c++) acc[r][c] += ar[r] * br[c];
    }
    __syncthreads();
  }
  // epilogue
  float4 bv0 = {0.f,0.f,0.f,0.f}, bv1 = {0.f,0.f,0.f,0.f};
  if (MODE != 0) {
    bv0 = *(const float4*)&bvec[bn + tx * 4];
    bv1 = *(const float4*)&bvec[bn + 64 + tx * 4];
  }
#pragma unroll
  for (int r = 0; r < 8; r++) {
    int row = bm + ((r >> 2) * 64) + ty * 4 + (r & 3);
    if (row >= M) continue;
    float* crow = C + (size_t)row * Nn;
#pragma unroll
    for (int hc = 0; hc < 2; hc++) {
      int col = bn + hc * 64 + tx * 4;
      float v0 = acc[r][hc * 4 + 0], v1 = acc[r][hc * 4 + 1];
      float v2 = acc[r][hc * 4 + 2], v3 = acc[r][hc * 4 + 3];
      float4 bv = hc ? bv1 : bv0;
      float4 o;
      if (MODE == 0) {
        o.x = silu_f(v0); o.y = silu_f(v1); o.z = silu_f(v2); o.w = silu_f(v3);
      } else if (MODE == 2) {
        o.x = v0 + bv.x; o.y = v1 + bv.y; o.z = v2 + bv.z; o.w = v3 + bv.w;
      } else {
        float4 old = *(const float4*)&crow[col];
        o.x = old.x + v0 + bv.x; o.y = old.y + v1 + bv.y;
        o.z = old.z + v2 + bv.z; o.w = old.w + v3 + bv.w;
      }
      *(float4*)&crow[col] = o;
    }
  }
}

// ---------------- fused causal silu-attention ----------------
// av[b,i,h*128+d] = sum_{j<=i} silu(q_i.k_j + bias[b,i,j]) / N * v_j[d]
__global__ __launch_bounds__(256) void attn_kernel(const float* __restrict__ act,
    const float* __restrict__ bias, float* __restrict__ av)
{
  __shared__ __align__(16) float Qs[32][132];
  __shared__ __align__(16) float Ks[32][132];
  __shared__ __align__(16) float Vs[32][132];
  __shared__ float Ws[32][33];
  int tid = threadIdx.x;
  int i0 = blockIdx.x * 32;
  int h = blockIdx.y;
  int b = blockIdx.z;

#pragma unroll
  for (int r = 0; r < 4; r++) {
    int id = tid + 256 * r;
    int row = id >> 5;
    int c4 = (id & 31) << 2;
    int gi = i0 + row;
    float4 q = {0.f,0.f,0.f,0.f};
    if (gi < SEQN) q = *(const float4*)&act[((size_t)(b * SEQN + gi)) * 4096 + h * HD + c4];
    *(float4*)&Qs[row][c4] = q;
  }
  float acc[16];
#pragma unroll
  for (int i = 0; i < 16; i++) acc[i] = 0.f;

  int jl = tid & 31;
  int ib = tid >> 5;
  int il = tid >> 3;
  int dg = tid & 7;

  for (int j0 = 0; j0 <= i0; j0 += 32) {
    __syncthreads();   // previous AV reads done before K/V overwrite
#pragma unroll
    for (int r = 0; r < 4; r++) {
      int id = tid + 256 * r;
      int row = id >> 5;
      int c4 = (id & 31) << 2;
      int gj = j0 + row;
      float4 kv = {0.f,0.f,0.f,0.f}, vv = {0.f,0.f,0.f,0.f};
      if (gj < SEQN) {
        const float* base = &act[((size_t)(b * SEQN + gj)) * 4096 + h * HD + c4];
        kv = *(const float4*)(base + 1024);
        vv = *(const float4*)(base + 2048);
      }
      *(float4*)&Ks[row][c4] = kv;
      *(float4*)&Vs[row][c4] = vv;
    }
    __syncthreads();
    // scores: thread -> (i in {ib, ib+8, ib+16, ib+24}, j = j0+jl)
    float sc[4] = {0.f,0.f,0.f,0.f};
#pragma unroll 8
    for (int c = 0; c < 32; c++) {
      float4 k4 = *(const float4*)&Ks[jl][c << 2];
#pragma unroll
      for (int ii = 0; ii < 4; ii++) {
        float4 q4 = *(const float4*)&Qs[ib + (ii << 3)][c << 2];
        sc[ii] += q4.x*k4.x + q4.y*k4.y + q4.z*k4.z + q4.w*k4.w;
      }
    }
    int gj = j0 + jl;
#pragma unroll
    for (int ii = 0; ii < 4; ii++) {
      int irow = ib + (ii << 3);
      int gi = i0 + irow;
      float w = 0.f;
      if (gi < SEQN && gj <= gi) {
        float s = sc[ii] + bias[((size_t)(b * SEQN + gi)) * SEQN + gj];
        w = s / (1.f + expf(-s)) * (1.f / (float)SEQN);
      }
      Ws[irow][jl] = w;
    }
    __syncthreads();
    // AV: thread -> (i = il, d block dg*16..dg*16+15)
#pragma unroll 8
    for (int jj = 0; jj < 32; jj++) {
      float w = Ws[il][jj];
      const float* vr = &Vs[jj][dg << 4];
#pragma unroll
      for (int c = 0; c < 4; c++) {
        float4 v4 = *(const float4*)(vr + (c << 2));
        acc[c*4+0] += w * v4.x;
        acc[c*4+1] += w * v4.y;
        acc[c*4+2] += w * v4.z;
        acc[c*4+3] += w * v4.w;
      }
    }
  }
  int gi = i0 + il;
  if (gi < SEQN) {
    float* dst = &av[((size_t)(b * SEQN + gi)) * DD + h * HD + (dg << 4)];
#pragma unroll
    for (int c = 0; c < 4; c++) {
      float4 o;
      o.x = acc[c*4+0]; o.y = acc[c*4+1]; o.z = acc[c*4+2]; o.w = acc[c*4+3];
      *(float4*)&dst[c << 2] = o;
    }
  }
}

// ---------------- launch ----------------
extern "C" void kernel_launch(void* const* d_in, const int* in_sizes, int n_in,
                              void* d_out, int out_size, void* d_ws, size_t ws_size,
                              hipStream_t stream) {
  const float* seqs  = (const float*)d_in[0];
  const int*   ts    = (const int*)d_in[2];
  const float* qkvuW = (const float*)d_in[3];
  const float* outW  = (const float*)d_in[4];
  const float* outB  = (const float*)d_in[5];
  const float* tsW   = (const float*)d_in[6];
  const float* posW  = (const float*)d_in[7];
  const float* fc1W  = (const float*)d_in[8];
  const float* fc1B  = (const float*)d_in[9];
  const float* fc2W  = (const float*)d_in[10];
  const float* fc2B  = (const float*)d_in[11];
  float* h = (float*)d_out;
  char* ws = (char*)d_ws;

  const size_t SZ_ROWD = (size_t)MROWS * DD * 4;        // 33,587,200
  const size_t SZ_ACT  = (size_t)MROWS * 4096 * 4;      // 134,348,800
  const size_t SZ_BIAS = (size_t)BB * SEQN * SEQN * 4;  // 33,620,000
  float* xn   = (float*)ws;
  float* act  = (float*)(ws + SZ_ROWD);
  float* bias = (float*)(ws + SZ_ROWD + SZ_ACT);
  float* av   = (float*)(ws + SZ_ROWD + SZ_ACT + SZ_BIAS);

  copy_kernel<<<2048, 256, 0, stream>>>(seqs, h, MROWS * DD / 4);

  for (int l = 0; l < LL; l++) {
    bias_kernel<<<dim3((SEQN + 255) / 256, SEQN, BB), 256, 0, stream>>>(
        ts, tsW + l * (NBUCKET + 1), posW + l * (2 * SEQN - 1), bias);
    ln_kernel<<<MROWS, 256, 0, stream>>>(h, xn);
    gemm_kernel<0, false><<<dim3(32, 65), 256, 0, stream>>>(
        xn, qkvuW + (size_t)l * DD * 4096, nullptr, act, MROWS, 4096, DD, DD);
    attn_kernel<<<dim3(33, HH, BB), 256, 0, stream>>>(act, bias, av);
    uln_kernel<<<MROWS, 256, 0, stream>>>(av, act, xn);
    gemm_kernel<1, false><<<dim3(8, 65), 256, 0, stream>>>(
        xn, outW + (size_t)l * DD * DD, outB + l * DD, h, MROWS, DD, DD, DD);
    rms_kernel<<<MROWS, 256, 0, stream>>>(h, xn);
    gemm_kernel<2, false><<<dim3(32, 65), 256, 0, stream>>>(
        xn, fc1W + (size_t)l * DD * 4096, fc1B + l * 4096, act, MROWS, 4096, DD, DD);
    gemm_kernel<1, true><<<dim3(8, 65), 256, 0, stream>>>(
        act, fc2W + (size_t)l * 2048 * DD, fc2B + l * DD, h, MROWS, DD, 2048, 4096);
  }
}

// Round 2
// 3896.453 us; speedup vs baseline: 2.5700x; 2.5700x over previous
//
#include <hip/hip_runtime.h>
#include <hip/hip_bf16.h>
#include <math.h>

#define BB 8
#define SEQN 1025
#define DD 1024
#define HH 8
#define HD 128
#define LL 2
#define MROWS (BB*SEQN)     // 8200
#define MPAD 8320           // 65 * 128
#define NBUCKET 64

using short8 = __attribute__((ext_vector_type(8))) short;
using f32x4  = __attribute__((ext_vector_type(4))) float;

__device__ __forceinline__ float silu_f(float x) { return x / (1.f + expf(-x)); }

__device__ __forceinline__ float bf2f(ushort u) {
  union { uint i; float f; } x; x.i = ((uint)u) << 16; return x.f;
}
__device__ __forceinline__ ushort f2bf(float f) {
  __hip_bfloat16 b = __float2bfloat16(f);
  return *reinterpret_cast<ushort*>(&b);
}
__device__ __forceinline__ void gll16(const void* g, void* l) {
  __builtin_amdgcn_global_load_lds((const __attribute__((address_space(1))) void*)g,
                                   (__attribute__((address_space(3))) void*)l, 16, 0, 0);
}

// ---------------- copy seqs -> h ----------------
__global__ __launch_bounds__(256) void copy_kernel(const float* __restrict__ in,
                                                   float* __restrict__ out, int n4) {
  int idx = blockIdx.x * blockDim.x + threadIdx.x;
  int stride = gridDim.x * blockDim.x;
  const float4* i4 = (const float4*)in;
  float4* o4 = (float4*)out;
  for (int i = idx; i < n4; i += stride) o4[i] = i4[i];
}

// ---------------- weight transpose+convert: W[K,N] f32 -> Wt[N,K] bf16 ----------------
__global__ __launch_bounds__(256) void wtrans(const float* __restrict__ W,
                                              ushort* __restrict__ Wt, int K, int N) {
  __shared__ float tile[32][33];
  int tid = threadIdx.x;
  int tx = tid & 31, ty = tid >> 5;           // 32 x 8
  int n0 = blockIdx.x * 32, k0 = blockIdx.y * 32;
#pragma unroll
  for (int r = 0; r < 32; r += 8)
    tile[ty + r][tx] = W[(size_t)(k0 + ty + r) * N + n0 + tx];
  __syncthreads();
#pragma unroll
  for (int r = 0; r < 32; r += 8)
    Wt[(size_t)(n0 + ty + r) * K + k0 + tx] = f2bf(tile[tx][ty + r]);
}

// ---------------- rel-attn bias [B,N,N] ----------------
__global__ __launch_bounds__(256) void bias_kernel(const int* __restrict__ ts,
    const float* __restrict__ ts_w, const float* __restrict__ pos_w,
    float* __restrict__ bias)
{
  int j = blockIdx.x * 256 + threadIdx.x;
  int i = blockIdx.y;
  int b = blockIdx.z;
  if (j >= SEQN) return;
  int ip1 = i + 1; if (ip1 > SEQN - 1) ip1 = SEQN - 1;
  long long t1 = (long long)ts[b * SEQN + ip1];
  long long t0 = (long long)ts[b * SEQN + j];
  long long d = t1 - t0;
  if (d < 0) d = -d;
  if (d < 1) d = 1;
  int bucket = (int)(logf((float)d) / 0.301f);
  if (bucket < 0) bucket = 0;
  if (bucket > NBUCKET) bucket = NBUCKET;
  bias[((size_t)(b * SEQN + i)) * SEQN + j] = pos_w[j - i + SEQN - 1] + ts_w[bucket];
}

// ---------------- row norms (f32 in, bf16 out) ----------------
__global__ __launch_bounds__(256) void ln_kernel(const float* __restrict__ in,
                                                 ushort* __restrict__ out) {
  int row = blockIdx.x;
  int tid = threadIdx.x;
  const float* x = in + (size_t)row * DD;
  float4 v = *(const float4*)&x[tid * 4];
  float s = v.x + v.y + v.z + v.w;
  float ss = v.x*v.x + v.y*v.y + v.z*v.z + v.w*v.w;
#pragma unroll
  for (int off = 32; off >= 1; off >>= 1) { s += __shfl_xor(s, off); ss += __shfl_xor(ss, off); }
  __shared__ float red0[4], red1[4];
  if ((tid & 63) == 0) { red0[tid >> 6] = s; red1[tid >> 6] = ss; }
  __syncthreads();
  s = red0[0] + red0[1] + red0[2] + red0[3];
  ss = red1[0] + red1[1] + red1[2] + red1[3];
  float mu = s * (1.f / DD);
  float var = fmaxf(ss * (1.f / DD) - mu * mu, 0.f);
  float inv = 1.f / sqrtf(var + 1e-8f);
  ushort4 o;
  o.x = f2bf((v.x - mu) * inv); o.y = f2bf((v.y - mu) * inv);
  o.z = f2bf((v.z - mu) * inv); o.w = f2bf((v.w - mu) * inv);
  *(ushort4*)&out[(size_t)row * DD + tid * 4] = o;
}

__global__ __launch_bounds__(256) void rms_kernel(const float* __restrict__ in,
                                                  ushort* __restrict__ out) {
  int row = blockIdx.x;
  int tid = threadIdx.x;
  const float* x = in + (size_t)row * DD;
  float4 v = *(const float4*)&x[tid * 4];
  float ss = v.x*v.x + v.y*v.y + v.z*v.z + v.w*v.w;
#pragma unroll
  for (int off = 32; off >= 1; off >>= 1) ss += __shfl_xor(ss, off);
  __shared__ float red1[4];
  if ((tid & 63) == 0) red1[tid >> 6] = ss;
  __syncthreads();
  ss = red1[0] + red1[1] + red1[2] + red1[3];
  float inv = 1.f / sqrtf(ss * (1.f / DD) + 1e-8f);
  ushort4 o;
  o.x = f2bf(v.x * inv); o.y = f2bf(v.y * inv);
  o.z = f2bf(v.z * inv); o.w = f2bf(v.w * inv);
  *(ushort4*)&out[(size_t)row * DD + tid * 4] = o;
}

// out[d] = u[d] * layernorm(av)[d]   (av f32, u bf16 from act, out bf16)
__global__ __launch_bounds__(256) void uln_kernel(const float* __restrict__ av,
    const ushort* __restrict__ act, ushort* __restrict__ out) {
  int row = blockIdx.x;
  int tid = threadIdx.x;
  const float* x = av + (size_t)row * DD;
  float4 v = *(const float4*)&x[tid * 4];
  float s = v.x + v.y + v.z + v.w;
  float ss = v.x*v.x + v.y*v.y + v.z*v.z + v.w*v.w;
#pragma unroll
  for (int off = 32; off >= 1; off >>= 1) { s += __shfl_xor(s, off); ss += __shfl_xor(ss, off); }
  __shared__ float red0[4], red1[4];
  if ((tid & 63) == 0) { red0[tid >> 6] = s; red1[tid >> 6] = ss; }
  __syncthreads();
  s = red0[0] + red0[1] + red0[2] + red0[3];
  ss = red1[0] + red1[1] + red1[2] + red1[3];
  float mu = s * (1.f / DD);
  float var = fmaxf(ss * (1.f / DD) - mu * mu, 0.f);
  float inv = 1.f / sqrtf(var + 1e-8f);
  ushort4 uu = *(const ushort4*)&act[(size_t)row * 4096 + 3072 + tid * 4];
  ushort4 o;
  o.x = f2bf(bf2f(uu.x) * (v.x - mu) * inv);
  o.y = f2bf(bf2f(uu.y) * (v.y - mu) * inv);
  o.z = f2bf(bf2f(uu.z) * (v.z - mu) * inv);
  o.w = f2bf(bf2f(uu.w) * (v.w - mu) * inv);
  *(ushort4*)&out[(size_t)row * DD + tid * 4] = o;
}

// ---------------- gated = silu(g)*v from fc1 act (bf16 in/out) ----------------
__global__ __launch_bounds__(256) void gated_kernel(const ushort* __restrict__ act,
                                                    ushort* __restrict__ gated) {
  int idx = blockIdx.x * 256 + threadIdx.x;
  const int total = MROWS * 2048 / 8;
  if (idx >= total) return;
  int row = idx >> 8;
  int col = (idx & 255) * 8;
  const ushort* base = act + (size_t)row * 4096;
  short8 vv = *(const short8*)(base + col);
  short8 gg = *(const short8*)(base + 2048 + col);
  short8 o;
#pragma unroll
  for (int j = 0; j < 8; ++j) {
    float v = bf2f((ushort)vv[j]);
    float g = bf2f((ushort)gg[j]);
    o[j] = (short)f2bf(silu_f(g) * v);
  }
  *(short8*)&gated[(size_t)row * 2048 + col] = o;
}

// ---------------- bf16 MFMA GEMM: C = op(A[M,K] @ Bt[N,K]^T) ----------------
// MODE 0: bf16 out = silu(x); MODE 1: f32 out += x + bvec; MODE 2: bf16 out = x + bvec
template<int MODE>
__global__ __launch_bounds__(256) void mgemm(const ushort* __restrict__ A,
    const ushort* __restrict__ Bt, const float* __restrict__ bvec,
    void* __restrict__ Cout, int M, int Nn, int K)
{
  __shared__ ushort As[2][4096];   // [buf][128 rows x 32 k] bf16, linear
  __shared__ ushort Bs[2][4096];
  const int tid  = threadIdx.x;
  const int lane = tid & 63, wave = tid >> 6;
  const int wm = wave >> 1, wn = wave & 1;
  const int lrow = lane & 15, lk = lane >> 4;   // frag row / k-quarter
  const int bm = blockIdx.y * 128, bn = blockIdx.x * 128;

  const int c0 = tid, c1 = tid + 256;           // 16B chunks (512 per tile)
  const ushort* Ag0 = A  + (size_t)(bm + (c0 >> 2)) * K + (c0 & 3) * 8;
  const ushort* Ag1 = A  + (size_t)(bm + (c1 >> 2)) * K + (c1 & 3) * 8;
  const ushort* Bg0 = Bt + (size_t)(bn + (c0 >> 2)) * K + (c0 & 3) * 8;
  const ushort* Bg1 = Bt + (size_t)(bn + (c1 >> 2)) * K + (c1 & 3) * 8;
  ushort* Ad0 = &As[0][c0 * 8];
  ushort* Ad1 = &As[0][c1 * 8];
  ushort* Bd0 = &Bs[0][c0 * 8];
  ushort* Bd1 = &Bs[0][c1 * 8];

  int aoff[4], boff[4];
#pragma unroll
  for (int m = 0; m < 4; ++m) aoff[m] = (wm * 64 + m * 16 + lrow) * 32 + lk * 8;
#pragma unroll
  for (int n = 0; n < 4; ++n) boff[n] = (wn * 64 + n * 16 + lrow) * 32 + lk * 8;

  f32x4 acc[4][4];
#pragma unroll
  for (int m = 0; m < 4; ++m)
#pragma unroll
    for (int n = 0; n < 4; ++n) acc[m][n] = (f32x4){0.f, 0.f, 0.f, 0.f};

  const int nk = K >> 5;
  gll16(Ag0, Ad0); gll16(Ag1, Ad1); gll16(Bg0, Bd0); gll16(Bg1, Bd1);
  int buf = 0;
  for (int kb = 0; kb < nk; ++kb) {
    __syncthreads();                 // drains vmcnt(0): buf ready; prev reads done
    if (kb + 1 < nk) {
      const int k0 = (kb + 1) << 5;
      const int bo = (buf ^ 1) * 4096;
      gll16(Ag0 + k0, Ad0 + bo); gll16(Ag1 + k0, Ad1 + bo);
      gll16(Bg0 + k0, Bd0 + bo); gll16(Bg1 + k0, Bd1 + bo);
    }
    short8 af[4], bfr[4];
#pragma unroll
    for (int m = 0; m < 4; ++m) af[m]  = *(const short8*)&As[buf][aoff[m]];
#pragma unroll
    for (int n = 0; n < 4; ++n) bfr[n] = *(const short8*)&Bs[buf][boff[n]];
#pragma unroll
    for (int m = 0; m < 4; ++m)
#pragma unroll
      for (int n = 0; n < 4; ++n)
        acc[m][n] = __builtin_amdgcn_mfma_f32_16x16x32_bf16(af[m], bfr[n], acc[m][n], 0, 0, 0);
    buf ^= 1;
  }

  // epilogue: D[row=(lane>>4)*4+reg][col=lane&15] per 16x16 frag (m89-verified)
  const int colbase = bn + wn * 64 + lrow;
  const int rowbase = bm + wm * 64 + lk * 4;
  if (MODE == 1) {
    float* Cf = (float*)Cout;
#pragma unroll
    for (int m = 0; m < 4; ++m) {
      int row0 = rowbase + m * 16;
#pragma unroll
      for (int n = 0; n < 4; ++n) {
        int col = colbase + n * 16;
        float bv = bvec[col];
#pragma unroll
        for (int r = 0; r < 4; ++r) {
          int row = row0 + r;
          if (row < M) {
            float* p = Cf + (size_t)row * Nn + col;
            *p += acc[m][n][r] + bv;
          }
        }
      }
    }
  } else {
    __hip_bfloat16* Cb = (__hip_bfloat16*)Cout;
#pragma unroll
    for (int m = 0; m < 4; ++m) {
      int row0 = rowbase + m * 16;
#pragma unroll
      for (int n = 0; n < 4; ++n) {
        int col = colbase + n * 16;
        float bv = (MODE == 2) ? bvec[col] : 0.f;
#pragma unroll
        for (int r = 0; r < 4; ++r) {
          int row = row0 + r;
          if (row < M) {
            float v = acc[m][n][r];
            float o = (MODE == 0) ? silu_f(v) : (v + bv);
            Cb[(size_t)row * Nn + col] = __float2bfloat16(o);
          }
        }
      }
    }
  }
}

// ---------------- fused causal silu-attention (bf16 act, f32 compute) ----------------
__global__ __launch_bounds__(256) void attn_kernel(const ushort* __restrict__ act,
    const float* __restrict__ bias, float* __restrict__ av)
{
  __shared__ __align__(16) float Qs[32][132];
  __shared__ __align__(16) float Ks[32][132];
  __shared__ __align__(16) float Vs[32][132];
  __shared__ float Ws[32][33];
  int tid = threadIdx.x;
  int i0 = (int)(gridDim.x - 1 - blockIdx.x) * 32;   // long blocks first
  int h = blockIdx.y;
  int b = blockIdx.z;
  short8 z8 = {0, 0, 0, 0, 0, 0, 0, 0};

  const int r0 = tid >> 4;            // 0..15
  const int cc = (tid & 15) * 8;      // 0..120

  // stage Q (bf16 -> f32 LDS)
#pragma unroll
  for (int half = 0; half < 2; ++half) {
    int row = r0 + half * 16;
    int gi = i0 + row;
    float4 f0 = {0,0,0,0}, f1 = {0,0,0,0};
    if (gi < SEQN) {
      short8 q = *(const short8*)&act[(size_t)(b * SEQN + gi) * 4096 + h * HD + cc];
      f0.x = bf2f((ushort)q[0]); f0.y = bf2f((ushort)q[1]);
      f0.z = bf2f((ushort)q[2]); f0.w = bf2f((ushort)q[3]);
      f1.x = bf2f((ushort)q[4]); f1.y = bf2f((ushort)q[5]);
      f1.z = bf2f((ushort)q[6]); f1.w = bf2f((ushort)q[7]);
    }
    *(float4*)&Qs[row][cc] = f0;
    *(float4*)&Qs[row][cc + 4] = f1;
  }

  float acc[16];
#pragma unroll
  for (int i = 0; i < 16; ++i) acc[i] = 0.f;

  const int jl = tid & 31;
  const int ibq = tid >> 5;
  const int il = tid >> 3;
  const int dg = tid & 7;

  short8 kr0, kr1, vr0, vr1;
  // prefetch tile 0
  {
    int gj0 = r0, gj1 = 16 + r0;
    const ushort* b0 = act + (size_t)(b * SEQN + gj0) * 4096 + h * HD + cc;
    const ushort* b1 = act + (size_t)(b * SEQN + gj1) * 4096 + h * HD + cc;
    kr0 = *(const short8*)(b0 + 1024); vr0 = *(const short8*)(b0 + 2048);
    kr1 = *(const short8*)(b1 + 1024); vr1 = *(const short8*)(b1 + 2048);
  }

  for (int j0 = 0; j0 <= i0; j0 += 32) {
    __syncthreads();   // prev AV reads of Vs done (and Q staged on iter 0)
    // write prefetched K/V to LDS (convert bf16->f32)
    {
      float4 f0, f1;
#define STROW(arr, ROW, REG)                                               \
      f0.x = bf2f((ushort)REG[0]); f0.y = bf2f((ushort)REG[1]);            \
      f0.z = bf2f((ushort)REG[2]); f0.w = bf2f((ushort)REG[3]);            \
      f1.x = bf2f((ushort)REG[4]); f1.y = bf2f((ushort)REG[5]);            \
      f1.z = bf2f((ushort)REG[6]); f1.w = bf2f((ushort)REG[7]);            \
      *(float4*)&arr[ROW][cc] = f0; *(float4*)&arr[ROW][cc + 4] = f1;
      STROW(Ks, r0, kr0) STROW(Ks, 16 + r0, kr1)
      STROW(Vs, r0, vr0) STROW(Vs, 16 + r0, vr1)
#undef STROW
    }
    __syncthreads();
    // prefetch next tile (latency hides under score+AV compute)
    if (j0 + 32 <= i0) {
      int gj0 = j0 + 32 + r0, gj1 = j0 + 48 + r0;
      if (gj0 < SEQN) {
        const ushort* b0 = act + (size_t)(b * SEQN + gj0) * 4096 + h * HD + cc;
        kr0 = *(const short8*)(b0 + 1024); vr0 = *(const short8*)(b0 + 2048);
      } else { kr0 = z8; vr0 = z8; }
      if (gj1 < SEQN) {
        const ushort* b1 = act + (size_t)(b * SEQN + gj1) * 4096 + h * HD + cc;
        kr1 = *(const short8*)(b1 + 1024); vr1 = *(const short8*)(b1 + 2048);
      } else { kr1 = z8; vr1 = z8; }
    }
    // scores
    float sc[4] = {0.f, 0.f, 0.f, 0.f};
#pragma unroll 8
    for (int c = 0; c < 32; ++c) {
      float4 k4 = *(const float4*)&Ks[jl][c << 2];
#pragma unroll
      for (int ii = 0; ii < 4; ++ii) {
        float4 q4 = *(const float4*)&Qs[ibq + (ii << 3)][c << 2];
        sc[ii] += q4.x * k4.x + q4.y * k4.y + q4.z * k4.z + q4.w * k4.w;
      }
    }
    int gj = j0 + jl;
#pragma unroll
    for (int ii = 0; ii < 4; ++ii) {
      int irow = ibq + (ii << 3);
      int gi = i0 + irow;
      float w = 0.f;
      if (gi < SEQN && gj <= gi) {
        float s = sc[ii] + bias[((size_t)(b * SEQN + gi)) * SEQN + gj];
        w = s / (1.f + expf(-s)) * (1.f / (float)SEQN);
      }
      Ws[irow][jl] = w;
    }
    __syncthreads();
    // AV
#pragma unroll 8
    for (int jj = 0; jj < 32; ++jj) {
      float w = Ws[il][jj];
      const float* vr = &Vs[jj][dg << 4];
#pragma unroll
      for (int c = 0; c < 4; ++c) {
        float4 v4 = *(const float4*)(vr + (c << 2));
        acc[c * 4 + 0] += w * v4.x;
        acc[c * 4 + 1] += w * v4.y;
        acc[c * 4 + 2] += w * v4.z;
        acc[c * 4 + 3] += w * v4.w;
      }
    }
  }
  int gi = i0 + il;
  if (gi < SEQN) {
    float* dst = &av[((size_t)(b * SEQN + gi)) * DD + h * HD + (dg << 4)];
#pragma unroll
    for (int c = 0; c < 4; ++c) {
      float4 o;
      o.x = acc[c * 4 + 0]; o.y = acc[c * 4 + 1];
      o.z = acc[c * 4 + 2]; o.w = acc[c * 4 + 3];
      *(float4*)&dst[c << 2] = o;
    }
  }
}

// ---------------- launch ----------------
extern "C" void kernel_launch(void* const* d_in, const int* in_sizes, int n_in,
                              void* d_out, int out_size, void* d_ws, size_t ws_size,
                              hipStream_t stream) {
  const float* seqs  = (const float*)d_in[0];
  const int*   ts    = (const int*)d_in[2];
  const float* qkvuW = (const float*)d_in[3];
  const float* outW  = (const float*)d_in[4];
  const float* outB  = (const float*)d_in[5];
  const float* tsW   = (const float*)d_in[6];
  const float* posW  = (const float*)d_in[7];
  const float* fc1W  = (const float*)d_in[8];
  const float* fc1B  = (const float*)d_in[9];
  const float* fc2W  = (const float*)d_in[10];
  const float* fc2B  = (const float*)d_in[11];
  float* h = (float*)d_out;
  char* ws = (char*)d_ws;

  // ws layout (bytes), all 16B-aligned; MPAD rows pad GEMM A-operands
  ushort* xn    = (ushort*)(ws);                 // 8320*1024*2  = 17,039,360
  ushort* act   = (ushort*)(ws + 17039360);      // 8320*4096*2  = 68,157,440
  ushort* gated = (ushort*)(ws + 85196800);      // 8320*2048*2  = 34,078,720
  float*  bias  = (float*) (ws + 119275520);     // 8*1025*1025*4= 33,620,000
  float*  av    = (float*) (ws + 152895520);     // 8200*1024*4  = 33,587,200
  ushort* wq    = (ushort*)(ws + 186482720);     // 4096*1024*2
  ushort* wo    = (ushort*)(ws + 194871328);     // 1024*1024*2
  ushort* wf1   = (ushort*)(ws + 196968480);     // 4096*1024*2
  ushort* wf2   = (ushort*)(ws + 205357088);     // 1024*2048*2

  copy_kernel<<<2048, 256, 0, stream>>>(seqs, h, MROWS * DD / 4);

  for (int l = 0; l < LL; l++) {
    wtrans<<<dim3(128, 32), 256, 0, stream>>>(qkvuW + (size_t)l * DD * 4096, wq, DD, 4096);
    wtrans<<<dim3(32, 32),  256, 0, stream>>>(outW  + (size_t)l * DD * DD,   wo, DD, DD);
    wtrans<<<dim3(128, 32), 256, 0, stream>>>(fc1W  + (size_t)l * DD * 4096, wf1, DD, 4096);
    wtrans<<<dim3(32, 64),  256, 0, stream>>>(fc2W  + (size_t)l * 2048 * DD, wf2, 2048, DD);

    bias_kernel<<<dim3(5, SEQN, BB), 256, 0, stream>>>(
        ts, tsW + l * (NBUCKET + 1), posW + l * (2 * SEQN - 1), bias);

    ln_kernel<<<MROWS, 256, 0, stream>>>(h, xn);
    mgemm<0><<<dim3(32, 65), 256, 0, stream>>>(xn, wq, nullptr, act, MROWS, 4096, DD);
    attn_kernel<<<dim3(33, HH, BB), 256, 0, stream>>>(act, bias, av);
    uln_kernel<<<MROWS, 256, 0, stream>>>(av, act, xn);
    mgemm<1><<<dim3(8, 65), 256, 0, stream>>>(xn, wo, outB + l * DD, h, MROWS, DD, DD);
    rms_kernel<<<MROWS, 256, 0, stream>>>(h, xn);
    mgemm<2><<<dim3(32, 65), 256, 0, stream>>>(xn, wf1, fc1B + (size_t)l * 4096, act, MROWS, 4096, DD);
    gated_kernel<<<8200, 256, 0, stream>>>(act, gated);
    mgemm<1><<<dim3(8, 65), 256, 0, stream>>>(gated, wf2, fc2B + l * DD, h, MROWS, DD, 2048);
  }
}

// Round 4
// 1099.291 us; speedup vs baseline: 9.1095x; 3.5445x over previous
//
#include <hip/hip_runtime.h>
#include <hip/hip_bf16.h>
#include <math.h>

#define BB 8
#define SEQN 1025
#define DD 1024
#define HH 8
#define HD 128
#define LL 2
#define MROWS (BB*SEQN)     // 8200
#define MPAD 8320           // 65 * 128
#define NBUCKET 64

using short8 = __attribute__((ext_vector_type(8))) short;
using f32x4  = __attribute__((ext_vector_type(4))) float;
using f32x16 = __attribute__((ext_vector_type(16))) float;

__device__ __forceinline__ float silu_f(float x) { return x / (1.f + expf(-x)); }

__device__ __forceinline__ float bf2f(ushort u) {
  union { uint i; float f; } x; x.i = ((uint)u) << 16; return x.f;
}
__device__ __forceinline__ ushort f2bf(float f) {
  __hip_bfloat16 b = __float2bfloat16(f);
  return *reinterpret_cast<ushort*>(&b);
}
__device__ __forceinline__ void gll16(const void* g, void* l) {
  __builtin_amdgcn_global_load_lds((const __attribute__((address_space(1))) void*)g,
                                   (__attribute__((address_space(3))) void*)l, 16, 0, 0);
}
__device__ __forceinline__ uint pkbf(float lo, float hi) {
  uint r;
  asm("v_cvt_pk_bf16_f32 %0, %1, %2" : "=v"(r) : "v"(lo), "v"(hi));
  return r;
}
__device__ __forceinline__ f32x16 z16() {
  f32x16 v;
#pragma unroll
  for (int i = 0; i < 16; ++i) v[i] = 0.f;
  return v;
}

// ---------------- copy seqs -> h ----------------
__global__ __launch_bounds__(256) void copy_kernel(const float* __restrict__ in,
                                                   float* __restrict__ out, int n4) {
  int idx = blockIdx.x * blockDim.x + threadIdx.x;
  int stride = gridDim.x * blockDim.x;
  const float4* i4 = (const float4*)in;
  float4* o4 = (float4*)out;
  for (int i = idx; i < n4; i += stride) o4[i] = i4[i];
}

// ---------------- weight transpose+convert: W[K,N] f32 -> Wt[N,K] bf16 ----------------
__global__ __launch_bounds__(256) void wtrans(const float* __restrict__ W,
                                              ushort* __restrict__ Wt, int K, int N) {
  __shared__ float tile[32][33];
  int tid = threadIdx.x;
  int tx = tid & 31, ty = tid >> 5;           // 32 x 8
  int n0 = blockIdx.x * 32, k0 = blockIdx.y * 32;
#pragma unroll
  for (int r = 0; r < 32; r += 8)
    tile[ty + r][tx] = W[(size_t)(k0 + ty + r) * N + n0 + tx];
  __syncthreads();
#pragma unroll
  for (int r = 0; r < 32; r += 8)
    Wt[(size_t)(n0 + ty + r) * K + k0 + tx] = f2bf(tile[tx][ty + r]);
}

// ---------------- rel-attn bias, stored TRANSPOSED: biasT[b][j][i] ----------------
__global__ __launch_bounds__(256) void bias_kernel(const int* __restrict__ ts,
    const float* __restrict__ ts_w, const float* __restrict__ pos_w,
    float* __restrict__ biasT)
{
  int i = blockIdx.x * 256 + threadIdx.x;
  int j = blockIdx.y;
  int b = blockIdx.z;
  if (i >= SEQN) return;
  int ip1 = i + 1; if (ip1 > SEQN - 1) ip1 = SEQN - 1;
  long long t1 = (long long)ts[b * SEQN + ip1];
  long long t0 = (long long)ts[b * SEQN + j];
  long long d = t1 - t0;
  if (d < 0) d = -d;
  if (d < 1) d = 1;
  int bucket = (int)(logf((float)d) / 0.301f);
  if (bucket < 0) bucket = 0;
  if (bucket > NBUCKET) bucket = NBUCKET;
  biasT[((size_t)(b * SEQN + j)) * SEQN + i] = pos_w[j - i + SEQN - 1] + ts_w[bucket];
}

// ---------------- row norms (f32 in, bf16 out) ----------------
__global__ __launch_bounds__(256) void ln_kernel(const float* __restrict__ in,
                                                 ushort* __restrict__ out) {
  int row = blockIdx.x;
  int tid = threadIdx.x;
  const float* x = in + (size_t)row * DD;
  float4 v = *(const float4*)&x[tid * 4];
  float s = v.x + v.y + v.z + v.w;
  float ss = v.x*v.x + v.y*v.y + v.z*v.z + v.w*v.w;
#pragma unroll
  for (int off = 32; off >= 1; off >>= 1) { s += __shfl_xor(s, off); ss += __shfl_xor(ss, off); }
  __shared__ float red0[4], red1[4];
  if ((tid & 63) == 0) { red0[tid >> 6] = s; red1[tid >> 6] = ss; }
  __syncthreads();
  s = red0[0] + red0[1] + red0[2] + red0[3];
  ss = red1[0] + red1[1] + red1[2] + red1[3];
  float mu = s * (1.f / DD);
  float var = fmaxf(ss * (1.f / DD) - mu * mu, 0.f);
  float inv = 1.f / sqrtf(var + 1e-8f);
  ushort4 o;
  o.x = f2bf((v.x - mu) * inv); o.y = f2bf((v.y - mu) * inv);
  o.z = f2bf((v.z - mu) * inv); o.w = f2bf((v.w - mu) * inv);
  *(ushort4*)&out[(size_t)row * DD + tid * 4] = o;
}

__global__ __launch_bounds__(256) void rms_kernel(const float* __restrict__ in,
                                                  ushort* __restrict__ out) {
  int row = blockIdx.x;
  int tid = threadIdx.x;
  const float* x = in + (size_t)row * DD;
  float4 v = *(const float4*)&x[tid * 4];
  float ss = v.x*v.x + v.y*v.y + v.z*v.z + v.w*v.w;
#pragma unroll
  for (int off = 32; off >= 1; off >>= 1) ss += __shfl_xor(ss, off);
  __shared__ float red1[4];
  if ((tid & 63) == 0) red1[tid >> 6] = ss;
  __syncthreads();
  ss = red1[0] + red1[1] + red1[2] + red1[3];
  float inv = 1.f / sqrtf(ss * (1.f / DD) + 1e-8f);
  ushort4 o;
  o.x = f2bf(v.x * inv); o.y = f2bf(v.y * inv);
  o.z = f2bf(v.z * inv); o.w = f2bf(v.w * inv);
  *(ushort4*)&out[(size_t)row * DD + tid * 4] = o;
}

// out[d] = u[d] * layernorm(av)[d]   (av f32, u bf16 from act, out bf16)
__global__ __launch_bounds__(256) void uln_kernel(const float* __restrict__ av,
    const ushort* __restrict__ act, ushort* __restrict__ out) {
  int row = blockIdx.x;
  int tid = threadIdx.x;
  const float* x = av + (size_t)row * DD;
  float4 v = *(const float4*)&x[tid * 4];
  float s = v.x + v.y + v.z + v.w;
  float ss = v.x*v.x + v.y*v.y + v.z*v.z + v.w*v.w;
#pragma unroll
  for (int off = 32; off >= 1; off >>= 1) { s += __shfl_xor(s, off); ss += __shfl_xor(ss, off); }
  __shared__ float red0[4], red1[4];
  if ((tid & 63) == 0) { red0[tid >> 6] = s; red1[tid >> 6] = ss; }
  __syncthreads();
  s = red0[0] + red0[1] + red0[2] + red0[3];
  ss = red1[0] + red1[1] + red1[2] + red1[3];
  float mu = s * (1.f / DD);
  float var = fmaxf(ss * (1.f / DD) - mu * mu, 0.f);
  float inv = 1.f / sqrtf(var + 1e-8f);
  ushort4 uu = *(const ushort4*)&act[(size_t)row * 4096 + 3072 + tid * 4];
  ushort4 o;
  o.x = f2bf(bf2f(uu.x) * (v.x - mu) * inv);
  o.y = f2bf(bf2f(uu.y) * (v.y - mu) * inv);
  o.z = f2bf(bf2f(uu.z) * (v.z - mu) * inv);
  o.w = f2bf(bf2f(uu.w) * (v.w - mu) * inv);
  *(ushort4*)&out[(size_t)row * DD + tid * 4] = o;
}

// ---------------- gated = silu(g)*v from fc1 act (bf16 in/out) ----------------
__global__ __launch_bounds__(256) void gated_kernel(const ushort* __restrict__ act,
                                                    ushort* __restrict__ gated) {
  int idx = blockIdx.x * 256 + threadIdx.x;
  const int total = MROWS * 2048 / 8;
  if (idx >= total) return;
  int row = idx >> 8;
  int col = (idx & 255) * 8;
  const ushort* base = act + (size_t)row * 4096;
  short8 vv = *(const short8*)(base + col);
  short8 gg = *(const short8*)(base + 2048 + col);
  short8 o;
#pragma unroll
  for (int j = 0; j < 8; ++j) {
    float v = bf2f((ushort)vv[j]);
    float g = bf2f((ushort)gg[j]);
    o[j] = (short)f2bf(silu_f(g) * v);
  }
  *(short8*)&gated[(size_t)row * 2048 + col] = o;
}

// ---------------- bf16 MFMA GEMM: C = op(A[M,K] @ Bt[N,K]^T) ----------------
// MODE 0: bf16 out = silu(x); MODE 1: f32 out += x + bvec; MODE 2: bf16 out = x + bvec
template<int MODE>
__global__ __launch_bounds__(256) void mgemm(const ushort* __restrict__ A,
    const ushort* __restrict__ Bt, const float* __restrict__ bvec,
    void* __restrict__ Cout, int M, int Nn, int K)
{
  __shared__ ushort As[2][4096];   // [buf][128 rows x 32 k] bf16, linear
  __shared__ ushort Bs[2][4096];
  const int tid  = threadIdx.x;
  const int lane = tid & 63, wave = tid >> 6;
  const int wm = wave >> 1, wn = wave & 1;
  const int lrow = lane & 15, lk = lane >> 4;   // frag row / k-quarter
  const int bm = blockIdx.y * 128, bn = blockIdx.x * 128;

  const int c0 = tid, c1 = tid + 256;           // 16B chunks (512 per tile)
  const ushort* Ag0 = A  + (size_t)(bm + (c0 >> 2)) * K + (c0 & 3) * 8;
  const ushort* Ag1 = A  + (size_t)(bm + (c1 >> 2)) * K + (c1 & 3) * 8;
  const ushort* Bg0 = Bt + (size_t)(bn + (c0 >> 2)) * K + (c0 & 3) * 8;
  const ushort* Bg1 = Bt + (size_t)(bn + (c1 >> 2)) * K + (c1 & 3) * 8;
  ushort* Ad0 = &As[0][c0 * 8];
  ushort* Ad1 = &As[0][c1 * 8];
  ushort* Bd0 = &Bs[0][c0 * 8];
  ushort* Bd1 = &Bs[0][c1 * 8];

  int aoff[4], boff[4];
#pragma unroll
  for (int m = 0; m < 4; ++m) aoff[m] = (wm * 64 + m * 16 + lrow) * 32 + lk * 8;
#pragma unroll
  for (int n = 0; n < 4; ++n) boff[n] = (wn * 64 + n * 16 + lrow) * 32 + lk * 8;

  f32x4 acc[4][4];
#pragma unroll
  for (int m = 0; m < 4; ++m)
#pragma unroll
    for (int n = 0; n < 4; ++n) acc[m][n] = (f32x4){0.f, 0.f, 0.f, 0.f};

  const int nk = K >> 5;
  gll16(Ag0, Ad0); gll16(Ag1, Ad1); gll16(Bg0, Bd0); gll16(Bg1, Bd1);
  int buf = 0;
  for (int kb = 0; kb < nk; ++kb) {
    __syncthreads();                 // drains vmcnt(0): buf ready; prev reads done
    if (kb + 1 < nk) {
      const int k0 = (kb + 1) << 5;
      const int bo = (buf ^ 1) * 4096;
      gll16(Ag0 + k0, Ad0 + bo); gll16(Ag1 + k0, Ad1 + bo);
      gll16(Bg0 + k0, Bd0 + bo); gll16(Bg1 + k0, Bd1 + bo);
    }
    short8 af[4], bfr[4];
#pragma unroll
    for (int m = 0; m < 4; ++m) af[m]  = *(const short8*)&As[buf][aoff[m]];
#pragma unroll
    for (int n = 0; n < 4; ++n) bfr[n] = *(const short8*)&Bs[buf][boff[n]];
#pragma unroll
    for (int m = 0; m < 4; ++m)
#pragma unroll
      for (int n = 0; n < 4; ++n)
        acc[m][n] = __builtin_amdgcn_mfma_f32_16x16x32_bf16(af[m], bfr[n], acc[m][n], 0, 0, 0);
    buf ^= 1;
  }

  // epilogue: D[row=(lane>>4)*4+reg][col=lane&15] per 16x16 frag (m89-verified)
  const int colbase = bn + wn * 64 + lrow;
  const int rowbase = bm + wm * 64 + lk * 4;
  if (MODE == 1) {
    float* Cf = (float*)Cout;
#pragma unroll
    for (int m = 0; m < 4; ++m) {
      int row0 = rowbase + m * 16;
#pragma unroll
      for (int n = 0; n < 4; ++n) {
        int col = colbase + n * 16;
        float bv = bvec[col];
#pragma unroll
        for (int r = 0; r < 4; ++r) {
          int row = row0 + r;
          if (row < M) {
            float* p = Cf + (size_t)row * Nn + col;
            *p += acc[m][n][r] + bv;
          }
        }
      }
    }
  } else {
    __hip_bfloat16* Cb = (__hip_bfloat16*)Cout;
#pragma unroll
    for (int m = 0; m < 4; ++m) {
      int row0 = rowbase + m * 16;
#pragma unroll
      for (int n = 0; n < 4; ++n) {
        int col = colbase + n * 16;
        float bv = (MODE == 2) ? bvec[col] : 0.f;
#pragma unroll
        for (int r = 0; r < 4; ++r) {
          int row = row0 + r;
          if (row < M) {
            float v = acc[m][n][r];
            float o = (MODE == 0) ? silu_f(v) : (v + bv);
            Cb[(size_t)row * Nn + col] = __float2bfloat16(o);
          }
        }
      }
    }
  }
}

// ---------------- MFMA causal silu-attention ----------------
// Per block: 128 q rows (4 waves x 32), one (b,h). KVBLK=32.
// Swapped QK^T (ST[j][q]) -> in-register silu/bias -> cvt_pk+permlane32_swap ->
// PV via ds_read_b64_tr_b16 on subtiled V. av[b,i,h*128+d] in f32.
__global__ __launch_bounds__(256) void attn_kernel(const ushort* __restrict__ act,
    const float* __restrict__ biasT, float* __restrict__ av)
{
  __shared__ __align__(16) char KL[8192];   // K: [32 j][128 d] bf16, 16B-slot ^ (j&15)
  __shared__ __align__(16) char VL[8320];   // V: [d/16][32 j][d%16] subtiles, 1040B each
  const int tid = threadIdx.x;
  const int l = tid & 63, w = tid >> 6;
  const int qi = (int)(gridDim.x - 1 - blockIdx.x);     // long blocks first
  const int i0 = qi * 128;
  const int h = blockIdx.y, b = blockIdx.z;
  const int lo31 = l & 31, hi = l >> 5;

  const int jlim = (i0 + 128 < SEQN) ? i0 + 128 : SEQN;
  const int nt = (jlim + 31) >> 5;

  // Q into registers: lane holds Q[q = i0+w*32+lo31][d = dc*16 + hi*8 + 0..7]
  const int gi_q = i0 + w * 32 + lo31;
  const int gi_qc = gi_q < SEQN ? gi_q : SEQN - 1;
  const size_t actB = (size_t)b * SEQN;
  const ushort* qrow = act + (actB + gi_qc) * 4096 + h * HD;
  short8 qreg[8];
#pragma unroll
  for (int dc = 0; dc < 8; ++dc)
    qreg[dc] = *(const short8*)(qrow + dc * 16 + hi * 8);

  f32x16 acc[4];
#pragma unroll
  for (int dt = 0; dt < 4; ++dt) acc[dt] = z16();

  // staging: 512 chunks (j = id>>4, c8 = (id&15)*8), 2 per thread
  const int id0 = tid, id1 = tid + 256;
  const int j_0 = id0 >> 4, c8_0 = (id0 & 15) * 8;
  const int j_1 = id1 >> 4, c8_1 = (id1 & 15) * 8;
  char* kw0 = KL + j_0 * 256 + (((id0 & 15) ^ (j_0 & 15)) << 4);
  char* kw1 = KL + j_1 * 256 + (((id1 & 15) ^ (j_1 & 15)) << 4);
  char* vw0 = VL + ((id0 & 15) >> 1) * 1040 + j_0 * 32 + (id0 & 1) * 16;
  char* vw1 = VL + ((id1 & 15) >> 1) * 1040 + j_1 * 32 + (id1 & 1) * 16;
  // tr-read per-lane base: each lane addresses its own 8B slot of the 4x16
  // subtile (row stride 32B -> (c>>2)*32 + (c&3)*8 == c*8)
  const uint vbase = (uint)(size_t)(__attribute__((address_space(3))) char*)
      (VL + ((l >> 4) & 1) * 1040 + hi * 256 + (l & 15) * 8);

  short8 kr0, kr1, vr0, vr1;
  {
    const ushort* p0 = act + (actB + j_0) * 4096 + 1024 + h * HD + c8_0;
    const ushort* p1 = act + (actB + j_1) * 4096 + 1024 + h * HD + c8_1;
    kr0 = *(const short8*)p0; vr0 = *(const short8*)(p0 + 1024);
    kr1 = *(const short8*)p1; vr1 = *(const short8*)(p1 + 1024);
  }
  const float invN = 1.f / (float)SEQN;
  const int gi0w = i0 + w * 32;

  for (int t = 0; t < nt; ++t) {
    const int j0 = t * 32;
    __syncthreads();                       // all waves done reading prev tile
    *(short8*)kw0 = kr0; *(short8*)kw1 = kr1;
    *(short8*)vw0 = vr0; *(short8*)vw1 = vr1;
    __syncthreads();
    if (t + 1 < nt) {                      // T14: prefetch next tile into regs
      const ushort* p0 = act + (actB + j0 + 32 + j_0) * 4096 + 1024 + h * HD + c8_0;
      const ushort* p1 = act + (actB + j0 + 32 + j_1) * 4096 + 1024 + h * HD + c8_1;
      kr0 = *(const short8*)p0; vr0 = *(const short8*)(p0 + 1024);
      kr1 = *(const short8*)p1; vr1 = *(const short8*)(p1 + 1024);
    }
    if (j0 <= gi0w + 31 && gi0w < SEQN) {  // wave-uniform causal skip
      // bias loads (early, hide under QK)
      float bv[16];
#pragma unroll
      for (int r = 0; r < 16; ++r) {
        int j = (r & 3) + 8 * (r >> 2) + 4 * hi;
        int gj = j0 + j;
        int gjc = gj < SEQN ? gj : SEQN - 1;
        bv[r] = biasT[(actB + gjc) * SEQN + gi_qc];
      }
      // QK^T swapped: ST[j][q] = sum_d K[j][d] Q[q][d]
      f32x16 st = z16();
#pragma unroll
      for (int dc = 0; dc < 8; ++dc) {
        short8 kf = *(const short8*)(KL + lo31 * 256 + ((((dc << 1) + hi) ^ (lo31 & 15)) << 4));
        st = __builtin_amdgcn_mfma_f32_32x32x16_bf16(kf, qreg[dc], st, 0, 0, 0);
      }
      // epilogue: p[r] = silu(st + bias)/N, causal-masked
      float p[16];
#pragma unroll
      for (int r = 0; r < 16; ++r) {
        int j = (r & 3) + 8 * (r >> 2) + 4 * hi;
        int gj = j0 + j;
        float s = st[r] + bv[r];
        float pw = s * __builtin_amdgcn_rcpf(1.f + __expf(-s)) * invN;
        p[r] = ((gj <= gi_q) && (gi_q < SEQN)) ? pw : 0.f;
      }
      // P^T -> A-fragments (m=q, k=j).
      // v_permlane32_swap_b32 A,B exchanges A's UPPER 32 lanes with B's LOWER 32.
      // w0=pk(p0,p1), w2=pk(p4,p5): after swap(w0,w2): w0=(j0,j1)|(j8,j9)=frag word0,
      // w2=(j4,j5)|(j12,j13)=frag word2. Same for (w1,w3). (T12 recipe)
      short8 paf[2];
#pragma unroll
      for (int g = 0; g < 2; ++g) {
        uint w0 = pkbf(p[g * 8 + 0], p[g * 8 + 1]);
        uint w2 = pkbf(p[g * 8 + 4], p[g * 8 + 5]);
        uint w1 = pkbf(p[g * 8 + 2], p[g * 8 + 3]);
        uint w3 = pkbf(p[g * 8 + 6], p[g * 8 + 7]);
        asm volatile("v_permlane32_swap_b32 %0, %1" : "+v"(w0), "+v"(w2));
        asm volatile("v_permlane32_swap_b32 %0, %1" : "+v"(w1), "+v"(w3));
        union UF { uint u[4]; short8 s; } uf;
        uf.u[0] = w0; uf.u[1] = w1; uf.u[2] = w2; uf.u[3] = w3;
        paf[g] = uf.s;
      }
      // V fragments: 16x tr-read (4 per d-tile: jh0{t0,t1}, jh1{t0,t1}), one wait.
      // offset(dt,jh,t) = dt*2080 + jh*512 + t*128
      uint64_t v00, v01, v02, v03, v10, v11, v12, v13, v20, v21, v22, v23, v30, v31, v32, v33;
      asm volatile(
        "ds_read_b64_tr_b16 %0, %16 offset:0\n\t"
        "ds_read_b64_tr_b16 %1, %16 offset:128\n\t"
        "ds_read_b64_tr_b16 %2, %16 offset:512\n\t"
        "ds_read_b64_tr_b16 %3, %16 offset:640\n\t"
        "ds_read_b64_tr_b16 %4, %16 offset:2080\n\t"
        "ds_read_b64_tr_b16 %5, %16 offset:2208\n\t"
        "ds_read_b64_tr_b16 %6, %16 offset:2592\n\t"
        "ds_read_b64_tr_b16 %7, %16 offset:2720\n\t"
        "ds_read_b64_tr_b16 %8, %16 offset:4160\n\t"
        "ds_read_b64_tr_b16 %9, %16 offset:4288\n\t"
        "ds_read_b64_tr_b16 %10, %16 offset:4672\n\t"
        "ds_read_b64_tr_b16 %11, %16 offset:4800\n\t"
        "ds_read_b64_tr_b16 %12, %16 offset:6240\n\t"
        "ds_read_b64_tr_b16 %13, %16 offset:6368\n\t"
        "ds_read_b64_tr_b16 %14, %16 offset:6752\n\t"
        "ds_read_b64_tr_b16 %15, %16 offset:6880\n\t"
        "s_waitcnt lgkmcnt(0)"
        : "=v"(v00), "=v"(v01), "=v"(v02), "=v"(v03),
          "=v"(v10), "=v"(v11), "=v"(v12), "=v"(v13),
          "=v"(v20), "=v"(v21), "=v"(v22), "=v"(v23),
          "=v"(v30), "=v"(v31), "=v"(v32), "=v"(v33)
        : "v"(vbase) : "memory");
      union UV { uint64_t q[2]; short8 s; };
      { UV uv; uv.q[0] = v00; uv.q[1] = v01;
        acc[0] = __builtin_amdgcn_mfma_f32_32x32x16_bf16(paf[0], uv.s, acc[0], 0, 0, 0); }
      { UV uv; uv.q[0] = v02; uv.q[1] = v03;
        acc[0] = __builtin_amdgcn_mfma_f32_32x32x16_bf16(paf[1], uv.s, acc[0], 0, 0, 0); }
      { UV uv; uv.q[0] = v10; uv.q[1] = v11;
        acc[1] = __builtin_amdgcn_mfma_f32_32x32x16_bf16(paf[0], uv.s, acc[1], 0, 0, 0); }
      { UV uv; uv.q[0] = v12; uv.q[1] = v13;
        acc[1] = __builtin_amdgcn_mfma_f32_32x32x16_bf16(paf[1], uv.s, acc[1], 0, 0, 0); }
      { UV uv; uv.q[0] = v20; uv.q[1] = v21;
        acc[2] = __builtin_amdgcn_mfma_f32_32x32x16_bf16(paf[0], uv.s, acc[2], 0, 0, 0); }
      { UV uv; uv.q[0] = v22; uv.q[1] = v23;
        acc[2] = __builtin_amdgcn_mfma_f32_32x32x16_bf16(paf[1], uv.s, acc[2], 0, 0, 0); }
      { UV uv; uv.q[0] = v30; uv.q[1] = v31;
        acc[3] = __builtin_amdgcn_mfma_f32_32x32x16_bf16(paf[0], uv.s, acc[3], 0, 0, 0); }
      { UV uv; uv.q[0] = v32; uv.q[1] = v33;
        acc[3] = __builtin_amdgcn_mfma_f32_32x32x16_bf16(paf[1], uv.s, acc[3], 0, 0, 0); }
    }
  }
  // store: D[m=q][n=d]: row q=(r&3)+8*(r>>2)+4*hi, col d = dt*32 + lo31
#pragma unroll
  for (int dt = 0; dt < 4; ++dt) {
#pragma unroll
    for (int r = 0; r < 16; ++r) {
      int q = (r & 3) + 8 * (r >> 2) + 4 * hi;
      int gi = i0 + w * 32 + q;
      if (gi < SEQN)
        av[(actB + gi) * DD + h * HD + dt * 32 + lo31] = acc[dt][r];
    }
  }
}

// ---------------- launch ----------------
extern "C" void kernel_launch(void* const* d_in, const int* in_sizes, int n_in,
                              void* d_out, int out_size, void* d_ws, size_t ws_size,
                              hipStream_t stream) {
  const float* seqs  = (const float*)d_in[0];
  const int*   ts    = (const int*)d_in[2];
  const float* qkvuW = (const float*)d_in[3];
  const float* outW  = (const float*)d_in[4];
  const float* outB  = (const float*)d_in[5];
  const float* tsW   = (const float*)d_in[6];
  const float* posW  = (const float*)d_in[7];
  const float* fc1W  = (const float*)d_in[8];
  const float* fc1B  = (const float*)d_in[9];
  const float* fc2W  = (const float*)d_in[10];
  const float* fc2B  = (const float*)d_in[11];
  float* h = (float*)d_out;
  char* ws = (char*)d_ws;

  // ws layout (bytes), all 16B-aligned; MPAD rows pad GEMM A-operands
  ushort* xn    = (ushort*)(ws);                 // 8320*1024*2  = 17,039,360
  ushort* act   = (ushort*)(ws + 17039360);      // 8320*4096*2  = 68,157,440
  ushort* gated = (ushort*)(ws + 85196800);      // 8320*2048*2  = 34,078,720
  float*  biasT = (float*) (ws + 119275520);     // 8*1025*1025*4= 33,620,000
  float*  av    = (float*) (ws + 152895520);     // 8200*1024*4  = 33,587,200
  ushort* wq    = (ushort*)(ws + 186482720);     // 4096*1024*2
  ushort* wo    = (ushort*)(ws + 194871328);     // 1024*1024*2
  ushort* wf1   = (ushort*)(ws + 196968480);     // 4096*1024*2
  ushort* wf2   = (ushort*)(ws + 205357088);     // 1024*2048*2

  copy_kernel<<<2048, 256, 0, stream>>>(seqs, h, MROWS * DD / 4);

  for (int l = 0; l < LL; l++) {
    wtrans<<<dim3(128, 32), 256, 0, stream>>>(qkvuW + (size_t)l * DD * 4096, wq, DD, 4096);
    wtrans<<<dim3(32, 32),  256, 0, stream>>>(outW  + (size_t)l * DD * DD,   wo, DD, DD);
    wtrans<<<dim3(128, 32), 256, 0, stream>>>(fc1W  + (size_t)l * DD * 4096, wf1, DD, 4096);
    wtrans<<<dim3(32, 64),  256, 0, stream>>>(fc2W  + (size_t)l * 2048 * DD, wf2, 2048, DD);

    bias_kernel<<<dim3(5, SEQN, BB), 256, 0, stream>>>(
        ts, tsW + l * (NBUCKET + 1), posW + l * (2 * SEQN - 1), biasT);

    ln_kernel<<<MROWS, 256, 0, stream>>>(h, xn);
    mgemm<0><<<dim3(32, 65), 256, 0, stream>>>(xn, wq, nullptr, act, MROWS, 4096, DD);
    attn_kernel<<<dim3(9, HH, BB), 256, 0, stream>>>(act, biasT, av);
    uln_kernel<<<MROWS, 256, 0, stream>>>(av, act, xn);
    mgemm<1><<<dim3(8, 65), 256, 0, stream>>>(xn, wo, outB + l * DD, h, MROWS, DD, DD);
    rms_kernel<<<MROWS, 256, 0, stream>>>(h, xn);
    mgemm<2><<<dim3(32, 65), 256, 0, stream>>>(xn, wf1, fc1B + (size_t)l * 4096, act, MROWS, 4096, DD);
    gated_kernel<<<8200, 256, 0, stream>>>(act, gated);
    mgemm<1><<<dim3(8, 65), 256, 0, stream>>>(gated, wf2, fc2B + l * DD, h, MROWS, DD, 2048);
  }
}